// Round 2
// baseline (1188.793 us; speedup 1.0000x reference)
//
#include <hip/hip_runtime.h>
#include <hip/hip_bf16.h>
#include <stdint.h>
#include <stddef.h>

#define NODES 100000
#define EDGES 1600000
#define NPB 64          // nodes per block in precompute
#define EDGE_GRID 1250  // 6250 chunks / 5 per block, exact
#define NCHUNK 6250     // EDGES / 256

typedef float f4 __attribute__((ext_vector_type(4)));
typedef unsigned short u16x8 __attribute__((ext_vector_type(8)));

__device__ __forceinline__ float bf2f(unsigned short u) {
  union { unsigned int i; float f; } v; v.i = ((unsigned int)u) << 16; return v.f;
}
__device__ __forceinline__ unsigned short f2bf(float f) {
  union { float f; unsigned int i; } v; v.f = f;
  unsigned int r = (v.i + 0x7FFFu + ((v.i >> 16) & 1u)) >> 16;  // RNE
  return (unsigned short)r;
}

// ---------------------------------------------------------------------------
// Kernel 1: PQ[n][j]     = z[n] @ W1[0:64, j]  + b1[j]   (j <  128, b1 folded)
//           PQ[n][128+j] = z[n] @ W1[64:128, j]          (j < 128)
// bf16 output. 64 nodes/block; z staged in LDS via coalesced f4 loads;
// each thread owns one output column (wcol in 64 VGPRs, amortized 64 nodes).
// ---------------------------------------------------------------------------
__global__ __launch_bounds__(256) void node_pq_kernel(
    const float* __restrict__ z, const float* __restrict__ W1,
    const float* __restrict__ b1, unsigned short* __restrict__ PQ) {
  __shared__ float sz[NPB * 64];  // 16 KB
  const int t = threadIdx.x;
  const int n0 = blockIdx.x * NPB;
#pragma unroll
  for (int it = 0; it < (NPB * 64 / 4) / 256; ++it) {  // 4 iters
    int idx = it * 256 + t;          // f4 index
    int node = n0 + (idx >> 4);      // 16 f4 per node row
    f4 v = {0.f, 0.f, 0.f, 0.f};
    if (node < NODES) v = ((const f4*)z)[(size_t)node * 16 + (idx & 15)];
    ((f4*)sz)[idx] = v;
  }
  const int j = t;  // 0..255: 0..127 -> P column, 128..255 -> Q column
  const float* wbase = (j < 128) ? (W1 + j) : (W1 + 64 * 128 + (j - 128));
  float wcol[64];
#pragma unroll
  for (int k = 0; k < 64; ++k) wcol[k] = wbase[(size_t)k * 128];
  const float bias = (j < 128) ? b1[j] : 0.f;
  __syncthreads();
#pragma unroll 1
  for (int n = 0; n < NPB; ++n) {
    if (n0 + n >= NODES) break;
    const f4* zr = (const f4*)(sz + n * 64);
    float a = bias;
#pragma unroll
    for (int k4 = 0; k4 < 16; ++k4) {
      f4 zv = zr[k4];
      a = fmaf(zv[0], wcol[k4 * 4 + 0], a);
      a = fmaf(zv[1], wcol[k4 * 4 + 1], a);
      a = fmaf(zv[2], wcol[k4 * 4 + 2], a);
      a = fmaf(zv[3], wcol[k4 * 4 + 3], a);
    }
    PQ[(size_t)(n0 + n) * 256 + j] = f2bf(a);
  }
}

// ---------------------------------------------------------------------------
// Kernel 2: one lane = one edge; weights in LDS (broadcast ds_read, no K$
// streaming); P/Q gathered in 128-B register batches (each L2 line fetched
// exactly once, 8 loads in flight).
// ---------------------------------------------------------------------------
__global__ __launch_bounds__(256, 2) void edge_mlp_kernel(
    const int* __restrict__ eidx, const float* __restrict__ eattr,
    const float* __restrict__ W1, const float* __restrict__ W2,
    const float* __restrict__ b2, const float* __restrict__ W3,
    const float* __restrict__ b3,
    const unsigned short* __restrict__ PQ, float* __restrict__ out) {
  __shared__ float sW2[128 * 64];   // 32 KB, row-major [j][i]
  __shared__ float sW1cT[128 * 8];  // 4 KB, transposed [j][a]
  __shared__ float sb2[64];
  __shared__ float sW3[64];
  const int t = threadIdx.x;
#pragma unroll 1
  for (int i = t; i < 128 * 64 / 4; i += 256) ((f4*)sW2)[i] = ((const f4*)W2)[i];
#pragma unroll 1
  for (int i = t; i < 1024; i += 256) {
    int jj = i >> 3, a = i & 7;
    sW1cT[i] = W1[(size_t)(128 + a) * 128 + jj];
  }
  if (t < 64) { sb2[t] = b2[t]; sW3[t] = W3[t]; }
  const float bias3 = b3[0];
  __syncthreads();

#pragma unroll 1
  for (int chunk = blockIdx.x; chunk < NCHUNK; chunk += EDGE_GRID) {
    const int e = chunk * 256 + t;
    const int src = eidx[e];
    const int dst = eidx[EDGES + e];
    float eav[8];
    {
      const f4* eap = (const f4*)(eattr + (size_t)e * 8);
      f4 ea0 = eap[0], ea1 = eap[1];
#pragma unroll
      for (int a = 0; a < 4; ++a) { eav[a] = ea0[a]; eav[4 + a] = ea1[a]; }
    }
    const u16x8* Pp = (const u16x8*)(PQ + (size_t)src * 256);
    const u16x8* Qp = (const u16x8*)(PQ + (size_t)dst * 256 + 128);

    float acc[64];
#pragma unroll
    for (int i = 0; i < 64; ++i) acc[i] = 0.f;

#pragma unroll 1
    for (int half = 0; half < 2; ++half) {
      u16x8 p[8], q[8];
#pragma unroll
      for (int c = 0; c < 8; ++c) { p[c] = Pp[half * 8 + c]; q[c] = Qp[half * 8 + c]; }
#pragma unroll
      for (int c = 0; c < 8; ++c) {
        float h[8];
#pragma unroll
        for (int ii = 0; ii < 8; ++ii) {
          const int jj = half * 64 + c * 8 + ii;
          float s = bf2f(p[c][ii]) + bf2f(q[c][ii]);  // b1 already folded in
          const f4* w1r = (const f4*)(sW1cT + jj * 8);
          f4 wA = w1r[0], wB = w1r[1];
          s = fmaf(eav[0], wA[0], s); s = fmaf(eav[1], wA[1], s);
          s = fmaf(eav[2], wA[2], s); s = fmaf(eav[3], wA[3], s);
          s = fmaf(eav[4], wB[0], s); s = fmaf(eav[5], wB[1], s);
          s = fmaf(eav[6], wB[2], s); s = fmaf(eav[7], wB[3], s);
          h[ii] = fmaxf(s, 0.f);
        }
#pragma unroll
        for (int ii = 0; ii < 8; ++ii) {
          const float hv = h[ii];
          const f4* w2r = (const f4*)(sW2 + (size_t)(half * 64 + c * 8 + ii) * 64);
#pragma unroll
          for (int i4 = 0; i4 < 16; ++i4) {
            f4 w = w2r[i4];
            acc[i4 * 4 + 0] = fmaf(hv, w[0], acc[i4 * 4 + 0]);
            acc[i4 * 4 + 1] = fmaf(hv, w[1], acc[i4 * 4 + 1]);
            acc[i4 * 4 + 2] = fmaf(hv, w[2], acc[i4 * 4 + 2]);
            acc[i4 * 4 + 3] = fmaf(hv, w[3], acc[i4 * 4 + 3]);
          }
        }
      }
    }
    float res = bias3;
#pragma unroll
    for (int i4 = 0; i4 < 16; ++i4) {
      f4 bb = ((const f4*)sb2)[i4];
      f4 ww = ((const f4*)sW3)[i4];
#pragma unroll
      for (int tt = 0; tt < 4; ++tt) {
        float h2 = fmaxf(acc[i4 * 4 + tt] + bb[tt], 0.f);
        res = fmaf(h2, ww[tt], res);
      }
    }
    out[e] = res;
  }
}

extern "C" void kernel_launch(void* const* d_in, const int* in_sizes, int n_in,
                              void* d_out, int out_size, void* d_ws, size_t ws_size,
                              hipStream_t stream) {
  const float* z     = (const float*)d_in[0];
  const int*   eidx  = (const int*)d_in[1];
  const float* eattr = (const float*)d_in[2];
  const float* W1    = (const float*)d_in[3];
  const float* b1    = (const float*)d_in[4];
  const float* W2    = (const float*)d_in[5];
  const float* b2    = (const float*)d_in[6];
  const float* W3    = (const float*)d_in[7];
  const float* b3    = (const float*)d_in[8];
  float* out = (float*)d_out;

  unsigned short* PQ = (unsigned short*)d_ws;  // 51.2 MB (validated fits in round 1)
  node_pq_kernel<<<(NODES + NPB - 1) / NPB, 256, 0, stream>>>(z, W1, b1, PQ);
  edge_mlp_kernel<<<EDGE_GRID, 256, 0, stream>>>(
      eidx, eattr, W1, W2, b2, W3, b3, PQ, out);
}

// Round 3
// 225.847 us; speedup vs baseline: 5.2637x; 5.2637x over previous
//
#include <hip/hip_runtime.h>
#include <hip/hip_bf16.h>
#include <stdint.h>
#include <stddef.h>

#define NODES 100000
#define EDGES 1600000
#define NPB 64
#define EDGE_GRID 1250
#define NCHUNK 6250  // EDGES / 256

typedef float f4 __attribute__((ext_vector_type(4)));
typedef float f32x4 __attribute__((ext_vector_type(4)));
typedef short s8v __attribute__((ext_vector_type(8)));     // bf16x8 MFMA frag
typedef unsigned short u16x8 __attribute__((ext_vector_type(8)));

__device__ __forceinline__ float bf2f(unsigned short u) {
  union { unsigned int i; float f; } v; v.i = ((unsigned int)u) << 16; return v.f;
}
__device__ __forceinline__ unsigned short f2bf(float f) {  // RNE, setup paths
  union { float f; unsigned int i; } v; v.f = f;
  return (unsigned short)((v.i + 0x7FFFu + ((v.i >> 16) & 1u)) >> 16);
}
__device__ __forceinline__ short f2bf_hw(float x) {        // hot path: HW cvt
  __hip_bfloat16 h = __float2bfloat16(x);
  union { __hip_bfloat16 h; short s; } u; u.h = h; return u.s;
}

// Column permutation for PQ storage so the edge kernel's per-(kt,g) read is one
// contiguous 16B load: jj = kt<<5 | h<<4 | g<<2 | jp  ->  off = kt<<5 | g<<3 | h<<2 | jp
__device__ __forceinline__ int pqperm(int jj) {
  return (jj & 0x60) | ((jj & 0x0C) << 1) | ((jj & 0x10) >> 2) | (jj & 3);
}

// ---------------------------------------------------------------------------
// Kernel 1: PQ[n][perm(j)] = z[n]@W1[0:64,j] + b1[j];  PQ[n][128+perm(j)] = z[n]@W1[64:128,j]
// ---------------------------------------------------------------------------
__global__ __launch_bounds__(256) void node_pq_kernel(
    const float* __restrict__ z, const float* __restrict__ W1,
    const float* __restrict__ b1, unsigned short* __restrict__ PQ) {
  __shared__ float sz[NPB * 64];
  const int t = threadIdx.x;
  const int n0 = blockIdx.x * NPB;
#pragma unroll
  for (int it = 0; it < 4; ++it) {
    int idx = it * 256 + t;
    int node = n0 + (idx >> 4);
    f4 v = {0.f, 0.f, 0.f, 0.f};
    if (node < NODES) v = ((const f4*)z)[(size_t)node * 16 + (idx & 15)];
    ((f4*)sz)[idx] = v;
  }
  const int j = t;
  const int jj = (j < 128) ? j : (j - 128);
  const int outcol = (j < 128) ? pqperm(jj) : (128 + pqperm(jj));
  const float* wbase = (j < 128) ? (W1 + jj) : (W1 + 64 * 128 + jj);
  float wcol[64];
#pragma unroll
  for (int k = 0; k < 64; ++k) wcol[k] = wbase[(size_t)k * 128];
  const float bias = (j < 128) ? b1[jj] : 0.f;
  __syncthreads();
#pragma unroll 1
  for (int n = 0; n < NPB; ++n) {
    if (n0 + n >= NODES) break;
    const f4* zr = (const f4*)(sz + n * 64);
    float a = bias;
#pragma unroll
    for (int k4 = 0; k4 < 16; ++k4) {
      f4 zv = zr[k4];
      a = fmaf(zv[0], wcol[k4 * 4 + 0], a);
      a = fmaf(zv[1], wcol[k4 * 4 + 1], a);
      a = fmaf(zv[2], wcol[k4 * 4 + 2], a);
      a = fmaf(zv[3], wcol[k4 * 4 + 3], a);
    }
    PQ[(size_t)(n0 + n) * 256 + outcol] = f2bf(a);
  }
}

// ---------------------------------------------------------------------------
// Kernel 2: MFMA edge kernel. Per wave: 16 edges per sub-tile, 4 sub-tiles/chunk.
// A-side: lane owns edge r=l&15; k-slot (g,j=4h+jp) <-> jj = 32kt+16h+4g+jp.
// E = ea@W1c via MFMA (E^T = W1c^T ea^T), C-layout matches A-slots exactly.
// Layer2: 4 kt x 4 nt mfma_16x16x32_bf16 into acc[4] (f32x4 each).
// ---------------------------------------------------------------------------
__global__ __launch_bounds__(256) void edge_mfma_kernel(
    const int* __restrict__ eidx, const float* __restrict__ eattr,
    const float* __restrict__ W1, const float* __restrict__ W2,
    const float* __restrict__ b2, const float* __restrict__ W3,
    const float* __restrict__ b3,
    const unsigned short* __restrict__ PQ, float* __restrict__ out) {
  const int t = threadIdx.x;
  const int lane = t & 63;
  const int w = t >> 6;
  const int r = lane & 15;   // edge row (A side), also N-col (C side)
  const int g = lane >> 4;   // k-group

  // Persistent W2 B-frags: bfrag[kt][nt][j] = bf16(W2[jj(kt,g,j)][nt*16+r])
  s8v bfrag[4][4];
#pragma unroll
  for (int kt = 0; kt < 4; ++kt)
#pragma unroll
    for (int nt = 0; nt < 4; ++nt) {
      s8v f;
#pragma unroll
      for (int jx = 0; jx < 8; ++jx) {
        int h = jx >> 2, jp = jx & 3;
        int jj = 32 * kt + 16 * h + 4 * g + jp;
        f[jx] = (short)f2bf(W2[(size_t)jj * 64 + nt * 16 + r]);
      }
      bfrag[kt][nt] = f;
    }
  // W1c A'-frags for the E-mfma: k-slot a = g*8+j; nonzero only for g==0 (a<8).
  s8v w1cf[8];
#pragma unroll
  for (int mt = 0; mt < 8; ++mt) {
    s8v f = {0, 0, 0, 0, 0, 0, 0, 0};
    if (g == 0) {
#pragma unroll
      for (int jx = 0; jx < 8; ++jx)
        f[jx] = (short)f2bf(W1[(size_t)(128 + jx) * 128 + 16 * mt + r]);
    }
    w1cf[mt] = f;
  }
  float b2v[4], w3v[4];
#pragma unroll
  for (int nt = 0; nt < 4; ++nt) { b2v[nt] = b2[nt * 16 + r]; w3v[nt] = W3[nt * 16 + r]; }
  const float bias3 = b3[0];
  const f32x4 zc = {0.f, 0.f, 0.f, 0.f};

#pragma unroll 1
  for (int chunk = blockIdx.x; chunk < NCHUNK; chunk += EDGE_GRID) {
    const int ebase = chunk * 256 + w * 64;
#pragma unroll 1
    for (int st = 0; st < 4; ++st) {
      const int e0 = ebase + st * 16;
      const int e = e0 + r;
      const int src = eidx[e];
      const int dst = eidx[EDGES + e];
      // B' (ea) frag: g==0 lanes carry the 8 attrs of edge r; others zero.
      s8v eaf = {0, 0, 0, 0, 0, 0, 0, 0};
      if (g == 0) {
        f4 a0 = ((const f4*)(eattr + (size_t)e * 8))[0];
        f4 a1 = ((const f4*)(eattr + (size_t)e * 8))[1];
        eaf[0] = f2bf_hw(a0[0]); eaf[1] = f2bf_hw(a0[1]);
        eaf[2] = f2bf_hw(a0[2]); eaf[3] = f2bf_hw(a0[3]);
        eaf[4] = f2bf_hw(a1[0]); eaf[5] = f2bf_hw(a1[1]);
        eaf[6] = f2bf_hw(a1[2]); eaf[7] = f2bf_hw(a1[3]);
      }
      const unsigned short* Pb = PQ + (size_t)src * 256;
      const unsigned short* Qb = PQ + (size_t)dst * 256 + 128;
      f32x4 acc[4] = {zc, zc, zc, zc};
#pragma unroll
      for (int kt = 0; kt < 4; ++kt) {
        f32x4 E0 = __builtin_amdgcn_mfma_f32_16x16x32_bf16(w1cf[2 * kt], eaf, zc, 0, 0, 0);
        f32x4 E1 = __builtin_amdgcn_mfma_f32_16x16x32_bf16(w1cf[2 * kt + 1], eaf, zc, 0, 0, 0);
        u16x8 p = *(const u16x8*)(Pb + 32 * kt + 8 * g);  // covers j=0..7 of this (kt,g)
        u16x8 q = *(const u16x8*)(Qb + 32 * kt + 8 * g);
        s8v af;
#pragma unroll
        for (int jp = 0; jp < 4; ++jp) {
          float s0 = bf2f(p[jp]) + bf2f(q[jp]) + E0[jp];
          af[jp] = f2bf_hw(fmaxf(s0, 0.f));
          float s1 = bf2f(p[4 + jp]) + bf2f(q[4 + jp]) + E1[jp];
          af[4 + jp] = f2bf_hw(fmaxf(s1, 0.f));
        }
#pragma unroll
        for (int nt = 0; nt < 4; ++nt)
          acc[nt] = __builtin_amdgcn_mfma_f32_16x16x32_bf16(af, bfrag[kt][nt], acc[nt], 0, 0, 0);
      }
      // Layer 3: lane holds C rows (edges) 4g+reg, col i = nt*16+r.
      float pr0 = 0.f, pr1 = 0.f, pr2 = 0.f, pr3 = 0.f;
#pragma unroll
      for (int nt = 0; nt < 4; ++nt) {
        pr0 = fmaf(fmaxf(acc[nt][0] + b2v[nt], 0.f), w3v[nt], pr0);
        pr1 = fmaf(fmaxf(acc[nt][1] + b2v[nt], 0.f), w3v[nt], pr1);
        pr2 = fmaf(fmaxf(acc[nt][2] + b2v[nt], 0.f), w3v[nt], pr2);
        pr3 = fmaf(fmaxf(acc[nt][3] + b2v[nt], 0.f), w3v[nt], pr3);
      }
#pragma unroll
      for (int m = 1; m < 16; m <<= 1) {
        pr0 += __shfl_xor(pr0, m);
        pr1 += __shfl_xor(pr1, m);
        pr2 += __shfl_xor(pr2, m);
        pr3 += __shfl_xor(pr3, m);
      }
      if (r < 4) {
        float v = (r == 0) ? pr0 : (r == 1) ? pr1 : (r == 2) ? pr2 : pr3;
        out[e0 + 4 * g + r] = v + bias3;
      }
    }
  }
}

extern "C" void kernel_launch(void* const* d_in, const int* in_sizes, int n_in,
                              void* d_out, int out_size, void* d_ws, size_t ws_size,
                              hipStream_t stream) {
  const float* z     = (const float*)d_in[0];
  const int*   eidx  = (const int*)d_in[1];
  const float* eattr = (const float*)d_in[2];
  const float* W1    = (const float*)d_in[3];
  const float* b1    = (const float*)d_in[4];
  const float* W2    = (const float*)d_in[5];
  const float* b2    = (const float*)d_in[6];
  const float* W3    = (const float*)d_in[7];
  const float* b3    = (const float*)d_in[8];
  float* out = (float*)d_out;

  unsigned short* PQ = (unsigned short*)d_ws;  // 51.2 MB
  node_pq_kernel<<<(NODES + NPB - 1) / NPB, 256, 0, stream>>>(z, W1, b1, PQ);
  edge_mfma_kernel<<<EDGE_GRID, 256, 0, stream>>>(
      eidx, eattr, W1, W2, b2, W3, b3, PQ, out);
}

// Round 4
// 213.561 us; speedup vs baseline: 5.5665x; 1.0575x over previous
//
#include <hip/hip_runtime.h>
#include <hip/hip_bf16.h>
#include <stdint.h>
#include <stddef.h>

#define NODES 100000
#define EDGES 1600000
#define NPB 64
#define EDGE_GRID 1250
#define NCHUNK 6250  // EDGES / 256

typedef float f4 __attribute__((ext_vector_type(4)));
typedef float f32x4 __attribute__((ext_vector_type(4)));
typedef short s8v __attribute__((ext_vector_type(8)));     // bf16x8 MFMA frag
typedef unsigned short u16x8 __attribute__((ext_vector_type(8)));

__device__ __forceinline__ float bf2f(unsigned short u) {
  union { unsigned int i; float f; } v; v.i = ((unsigned int)u) << 16; return v.f;
}
__device__ __forceinline__ unsigned short f2bf(float f) {  // RNE, setup paths
  union { float f; unsigned int i; } v; v.f = f;
  return (unsigned short)((v.i + 0x7FFFu + ((v.i >> 16) & 1u)) >> 16);
}
__device__ __forceinline__ short f2bf_hw(float x) {        // hot path: HW cvt
  __hip_bfloat16 h = __float2bfloat16(x);
  union { __hip_bfloat16 h; short s; } u; u.h = h; return u.s;
}

// PQ column permutation: jj = kt<<5 | h<<4 | g<<2 | jp  ->  off = kt<<5 | g<<3 | h<<2 | jp
__device__ __forceinline__ int pqperm(int jj) {
  return (jj & 0x60) | ((jj & 0x0C) << 1) | ((jj & 0x10) >> 2) | (jj & 3);
}

// ---------------------------------------------------------------------------
// Kernel 1: PQ[n][perm(j)] = z[n]@W1[0:64,j] + b1[j];  PQ[n][128+perm(j)] = z[n]@W1[64:128,j]
// ---------------------------------------------------------------------------
__global__ __launch_bounds__(256) void node_pq_kernel(
    const float* __restrict__ z, const float* __restrict__ W1,
    const float* __restrict__ b1, unsigned short* __restrict__ PQ) {
  __shared__ float sz[NPB * 64];
  const int t = threadIdx.x;
  const int n0 = blockIdx.x * NPB;
#pragma unroll
  for (int it = 0; it < 4; ++it) {
    int idx = it * 256 + t;
    int node = n0 + (idx >> 4);
    f4 v = {0.f, 0.f, 0.f, 0.f};
    if (node < NODES) v = ((const f4*)z)[(size_t)node * 16 + (idx & 15)];
    ((f4*)sz)[idx] = v;
  }
  const int j = t;
  const int jj = (j < 128) ? j : (j - 128);
  const int outcol = (j < 128) ? pqperm(jj) : (128 + pqperm(jj));
  const float* wbase = (j < 128) ? (W1 + jj) : (W1 + 64 * 128 + jj);
  float wcol[64];
#pragma unroll
  for (int k = 0; k < 64; ++k) wcol[k] = wbase[(size_t)k * 128];
  const float bias = (j < 128) ? b1[jj] : 0.f;
  __syncthreads();
#pragma unroll 1
  for (int n = 0; n < NPB; ++n) {
    if (n0 + n >= NODES) break;
    const f4* zr = (const f4*)(sz + n * 64);
    float a = bias;
#pragma unroll
    for (int k4 = 0; k4 < 16; ++k4) {
      f4 zv = zr[k4];
      a = fmaf(zv[0], wcol[k4 * 4 + 0], a);
      a = fmaf(zv[1], wcol[k4 * 4 + 1], a);
      a = fmaf(zv[2], wcol[k4 * 4 + 2], a);
      a = fmaf(zv[3], wcol[k4 * 4 + 3], a);
    }
    PQ[(size_t)(n0 + n) * 256 + outcol] = f2bf(a);
  }
}

// ---------------------------------------------------------------------------
// Kernel 2: MFMA edge kernel, chunk-level coalesced index/attr loads + shuffle
// distribution; st loop fully unrolled so PQ gathers of all 4 sub-tiles can
// overlap (compiler-scheduled depth).
// ---------------------------------------------------------------------------
__global__ __launch_bounds__(256) void edge_mfma_kernel(
    const int* __restrict__ eidx, const float* __restrict__ eattr,
    const float* __restrict__ W1, const float* __restrict__ W2,
    const float* __restrict__ b2, const float* __restrict__ W3,
    const float* __restrict__ b3,
    const unsigned short* __restrict__ PQ, float* __restrict__ out) {
  const int t = threadIdx.x;
  const int lane = t & 63;
  const int w = t >> 6;
  const int r = lane & 15;   // edge row (A side) / N-col (C side)
  const int g = lane >> 4;   // k-group

  // Persistent W2 B-frags
  s8v bfrag[4][4];
#pragma unroll
  for (int kt = 0; kt < 4; ++kt)
#pragma unroll
    for (int nt = 0; nt < 4; ++nt) {
      s8v f;
#pragma unroll
      for (int jx = 0; jx < 8; ++jx) {
        int h = jx >> 2, jp = jx & 3;
        int jjv = 32 * kt + 16 * h + 4 * g + jp;
        f[jx] = (short)f2bf(W2[(size_t)jjv * 64 + nt * 16 + r]);
      }
      bfrag[kt][nt] = f;
    }
  // W1c A-frags for the E-mfma (k-slot = 8g+jx; nonzero only g==0).
  s8v w1cf[8];
#pragma unroll
  for (int mt = 0; mt < 8; ++mt) {
    s8v f = {0, 0, 0, 0, 0, 0, 0, 0};
    if (g == 0) {
#pragma unroll
      for (int jx = 0; jx < 8; ++jx)
        f[jx] = (short)f2bf(W1[(size_t)(128 + jx) * 128 + 16 * mt + r]);
    }
    w1cf[mt] = f;
  }
  float b2v[4], w3v[4];
#pragma unroll
  for (int nt = 0; nt < 4; ++nt) { b2v[nt] = b2[nt * 16 + r]; w3v[nt] = W3[nt * 16 + r]; }
  const float bias3 = b3[0];
  const f32x4 zc = {0.f, 0.f, 0.f, 0.f};

#pragma unroll 1
  for (int chunk = blockIdx.x; chunk < NCHUNK; chunk += EDGE_GRID) {
    const int ebase = chunk * 256 + w * 64;
    // Chunk-level coalesced loads: this wave's 64 edges.
    const int src_all = eidx[ebase + lane];
    const int dst_all = eidx[EDGES + ebase + lane];
    unsigned int ea_pk[4];
    {
      const f4* eap = (const f4*)(eattr + (size_t)(ebase + lane) * 8);
      f4 a0 = eap[0], a1 = eap[1];
      ea_pk[0] = (unsigned int)(unsigned short)f2bf_hw(a0[0]) |
                 ((unsigned int)(unsigned short)f2bf_hw(a0[1]) << 16);
      ea_pk[1] = (unsigned int)(unsigned short)f2bf_hw(a0[2]) |
                 ((unsigned int)(unsigned short)f2bf_hw(a0[3]) << 16);
      ea_pk[2] = (unsigned int)(unsigned short)f2bf_hw(a1[0]) |
                 ((unsigned int)(unsigned short)f2bf_hw(a1[1]) << 16);
      ea_pk[3] = (unsigned int)(unsigned short)f2bf_hw(a1[2]) |
                 ((unsigned int)(unsigned short)f2bf_hw(a1[3]) << 16);
    }

#pragma unroll
    for (int st = 0; st < 4; ++st) {
      const int e0 = ebase + st * 16;
      const int idx = st * 16 + r;
      const int srcv = __shfl(src_all, idx, 64);
      const int dstv = __shfl(dst_all, idx, 64);
      // eaf via shuffle of packed attrs (g!=0 lanes harmless: A is zero there)
      s8v eaf;
#pragma unroll
      for (int c = 0; c < 4; ++c) {
        unsigned int pk = (unsigned int)__shfl((int)ea_pk[c], idx, 64);
        eaf[2 * c] = (short)(pk & 0xFFFFu);
        eaf[2 * c + 1] = (short)(pk >> 16);
      }
      const unsigned short* Pb = PQ + (size_t)srcv * 256 + 8 * g;
      const unsigned short* Qb = PQ + (size_t)dstv * 256 + 128 + 8 * g;
      u16x8 p[4], q[4];
#pragma unroll
      for (int kt = 0; kt < 4; ++kt) {
        p[kt] = *(const u16x8*)(Pb + 32 * kt);
        q[kt] = *(const u16x8*)(Qb + 32 * kt);
      }
      f32x4 acc[4] = {zc, zc, zc, zc};
#pragma unroll
      for (int kt = 0; kt < 4; ++kt) {
        f32x4 E0 = __builtin_amdgcn_mfma_f32_16x16x32_bf16(w1cf[2 * kt], eaf, zc, 0, 0, 0);
        f32x4 E1 = __builtin_amdgcn_mfma_f32_16x16x32_bf16(w1cf[2 * kt + 1], eaf, zc, 0, 0, 0);
        s8v af;
#pragma unroll
        for (int jp = 0; jp < 4; ++jp) {
          float s0 = bf2f(p[kt][jp]) + bf2f(q[kt][jp]) + E0[jp];
          af[jp] = f2bf_hw(fmaxf(s0, 0.f));
          float s1 = bf2f(p[kt][4 + jp]) + bf2f(q[kt][4 + jp]) + E1[jp];
          af[4 + jp] = f2bf_hw(fmaxf(s1, 0.f));
        }
#pragma unroll
        for (int nt = 0; nt < 4; ++nt)
          acc[nt] = __builtin_amdgcn_mfma_f32_16x16x32_bf16(af, bfrag[kt][nt], acc[nt], 0, 0, 0);
      }
      // Layer 3 + 16-lane butterfly
      float pr0 = 0.f, pr1 = 0.f, pr2 = 0.f, pr3 = 0.f;
#pragma unroll
      for (int nt = 0; nt < 4; ++nt) {
        pr0 = fmaf(fmaxf(acc[nt][0] + b2v[nt], 0.f), w3v[nt], pr0);
        pr1 = fmaf(fmaxf(acc[nt][1] + b2v[nt], 0.f), w3v[nt], pr1);
        pr2 = fmaf(fmaxf(acc[nt][2] + b2v[nt], 0.f), w3v[nt], pr2);
        pr3 = fmaf(fmaxf(acc[nt][3] + b2v[nt], 0.f), w3v[nt], pr3);
      }
#pragma unroll
      for (int m = 1; m < 16; m <<= 1) {
        pr0 += __shfl_xor(pr0, m, 64);
        pr1 += __shfl_xor(pr1, m, 64);
        pr2 += __shfl_xor(pr2, m, 64);
        pr3 += __shfl_xor(pr3, m, 64);
      }
      if (r < 4) {
        float v = (r == 0) ? pr0 : (r == 1) ? pr1 : (r == 2) ? pr2 : pr3;
        out[e0 + 4 * g + r] = v + bias3;
      }
    }
  }
}

extern "C" void kernel_launch(void* const* d_in, const int* in_sizes, int n_in,
                              void* d_out, int out_size, void* d_ws, size_t ws_size,
                              hipStream_t stream) {
  const float* z     = (const float*)d_in[0];
  const int*   eidx  = (const int*)d_in[1];
  const float* eattr = (const float*)d_in[2];
  const float* W1    = (const float*)d_in[3];
  const float* b1    = (const float*)d_in[4];
  const float* W2    = (const float*)d_in[5];
  const float* b2    = (const float*)d_in[6];
  const float* W3    = (const float*)d_in[7];
  const float* b3    = (const float*)d_in[8];
  float* out = (float*)d_out;

  unsigned short* PQ = (unsigned short*)d_ws;  // 51.2 MB
  node_pq_kernel<<<(NODES + NPB - 1) / NPB, 256, 0, stream>>>(z, W1, b1, PQ);
  edge_mfma_kernel<<<EDGE_GRID, 256, 0, stream>>>(
      eidx, eattr, W1, W2, b2, W3, b3, PQ, out);
}

// Round 5
// 201.265 us; speedup vs baseline: 5.9066x; 1.0611x over previous
//
#include <hip/hip_runtime.h>
#include <hip/hip_bf16.h>
#include <stdint.h>
#include <stddef.h>

#define NODES 100000
#define EDGES 1600000
#define NCHUNK 6250    // EDGES / 256
#define EDGE_GRID 3125 // 2 chunks per block, exact
#define NTILES 6250    // NODES / 16, exact

typedef float f4 __attribute__((ext_vector_type(4)));
typedef float f32x4 __attribute__((ext_vector_type(4)));
typedef short s8v __attribute__((ext_vector_type(8)));     // bf16x8 MFMA frag
typedef unsigned short u16x8 __attribute__((ext_vector_type(8)));

__device__ __forceinline__ float bf2f(unsigned short u) {
  union { unsigned int i; float f; } v; v.i = ((unsigned int)u) << 16; return v.f;
}
__device__ __forceinline__ unsigned short f2bf(float f) {  // RNE (setup/stores)
  union { float f; unsigned int i; } v; v.f = f;
  return (unsigned short)((v.i + 0x7FFFu + ((v.i >> 16) & 1u)) >> 16);
}
__device__ __forceinline__ short f2bf_hw(float x) {        // hot path: HW cvt
  __hip_bfloat16 h = __float2bfloat16(x);
  union { __hip_bfloat16 h; short s; } u; u.h = h; return u.s;
}

// ---------------------------------------------------------------------------
// Kernel 1 (MFMA): PQ[n][jj]      = z[n] @ W1[0:64,jj]  + b1[jj]
//                  PQ[n][128+jj]  = z[n] @ W1[64:128,jj]
// Natural jj order (the edge kernel's B-operand gather wants exactly this).
// z and W1 split hi/lo bf16, 3-term MFMA products => f32-grade precision.
// One wave per 16-node tile.
// ---------------------------------------------------------------------------
__global__ __launch_bounds__(256) void node_pq_mfma(
    const float* __restrict__ z, const float* __restrict__ W1,
    const float* __restrict__ b1, unsigned short* __restrict__ PQ) {
  const int t = threadIdx.x;
  const int lane = t & 63;
  const int w = t >> 6;
  const int r = lane & 15, g = lane >> 4;
  const int tile = blockIdx.x * 4 + w;
  if (tile >= NTILES) return;
  const int n0 = tile * 16;

  // A-frags: A[row=node r][k=32kt+8g+jx], hi/lo split
  s8v a_hi[2], a_lo[2];
#pragma unroll
  for (int kt = 0; kt < 2; ++kt) {
    const f4* zp = (const f4*)(z + (size_t)(n0 + r) * 64 + 32 * kt + 8 * g);
    f4 z0 = zp[0], z1 = zp[1];
    float zv[8] = {z0[0], z0[1], z0[2], z0[3], z1[0], z1[1], z1[2], z1[3]};
    s8v hi, lo;
#pragma unroll
    for (int jx = 0; jx < 8; ++jx) {
      short h = f2bf_hw(zv[jx]);
      hi[jx] = h;
      lo[jx] = f2bf_hw(zv[jx] - bf2f((unsigned short)h));
    }
    a_hi[kt] = hi; a_lo[kt] = lo;
  }

#pragma unroll 1
  for (int nt = 0; nt < 16; ++nt) {
    const int col = (nt & 7) * 16 + r;
    const int rowbase = (nt < 8) ? 0 : 64;
    const float init = (nt < 8) ? b1[col] : 0.f;
    f32x4 acc = {init, init, init, init};
#pragma unroll
    for (int kt = 0; kt < 2; ++kt) {
      s8v whi, wlo;
#pragma unroll
      for (int jx = 0; jx < 8; ++jx) {
        float wv = W1[(size_t)(rowbase + 32 * kt + 8 * g + jx) * 128 + col];
        short h = f2bf_hw(wv);
        whi[jx] = h;
        wlo[jx] = f2bf_hw(wv - bf2f((unsigned short)h));
      }
      acc = __builtin_amdgcn_mfma_f32_16x16x32_bf16(a_hi[kt], whi, acc, 0, 0, 0);
      acc = __builtin_amdgcn_mfma_f32_16x16x32_bf16(a_lo[kt], whi, acc, 0, 0, 0);
      acc = __builtin_amdgcn_mfma_f32_16x16x32_bf16(a_hi[kt], wlo, acc, 0, 0, 0);
    }
    // C: lane (g,r) reg -> node n0+4g+reg, column nt*16+r (Q region = nt>=8)
#pragma unroll
    for (int reg = 0; reg < 4; ++reg)
      PQ[(size_t)(n0 + 4 * g + reg) * 256 + nt * 16 + r] = f2bf(acc[reg]);
  }
}

// ---------------------------------------------------------------------------
// Kernel 2: MFMA edge kernel with identity-pair S-mfma:
//   E  = W1c^T @ ea^T            (C layout rows=jj', cols=edges)
//   S  = mfma(a_id, [P;Q], E)    => P+Q+E in f32, zero VALU adds
//   af = cvt(relu(S)); layer2 = 16 mfma; layer3 = butterfly
// ---------------------------------------------------------------------------
__global__ __launch_bounds__(256) void edge_mfma_kernel(
    const int* __restrict__ eidx, const float* __restrict__ eattr,
    const float* __restrict__ W1, const float* __restrict__ W2,
    const float* __restrict__ b2, const float* __restrict__ W3,
    const float* __restrict__ b3,
    const unsigned short* __restrict__ PQ, float* __restrict__ out) {
  const int t = threadIdx.x;
  const int lane = t & 63;
  const int w = t >> 6;
  const int r = lane & 15;   // edge row (A side) / col (C side)
  const int g = lane >> 4;   // k-group

  // Persistent W2 B-frags: jj(kt,g,jx) = 32kt + 16(jx>>2) + 4g + (jx&3)
  s8v bfrag[4][4];
#pragma unroll
  for (int kt = 0; kt < 4; ++kt)
#pragma unroll
    for (int nt = 0; nt < 4; ++nt) {
      s8v f;
#pragma unroll
      for (int jx = 0; jx < 8; ++jx) {
        int h = jx >> 2, jp = jx & 3;
        int jjv = 32 * kt + 16 * h + 4 * g + jp;
        f[jx] = (short)f2bf(W2[(size_t)jjv * 64 + nt * 16 + r]);
      }
      bfrag[kt][nt] = f;
    }
  // W1c A-frags for the E-mfma (k-slot = 8g+jx; nonzero only g==0).
  s8v w1cf[8];
#pragma unroll
  for (int mt = 0; mt < 8; ++mt) {
    s8v f = {0, 0, 0, 0, 0, 0, 0, 0};
    if (g == 0) {
#pragma unroll
      for (int jx = 0; jx < 8; ++jx)
        f[jx] = (short)f2bf(W1[(size_t)(128 + jx) * 128 + 16 * mt + r]);
    }
    w1cf[mt] = f;
  }
  // Identity-pair A for the S-mfma: A[row=r][k] = 1 at k=r (P) and k=16+r (Q).
  // Lane (g,r) holds k=8g+jx  =>  nonzero iff (g&1)==(r>>3) at jx=r&7.
  s8v a_id = {0, 0, 0, 0, 0, 0, 0, 0};
  if ((g & 1) == (r >> 3)) a_id[r & 7] = (short)0x3F80;  // bf16 1.0

  float b2v[4], w3v[4];
#pragma unroll
  for (int nt = 0; nt < 4; ++nt) { b2v[nt] = b2[nt * 16 + r]; w3v[nt] = W3[nt * 16 + r]; }
  const float bias3 = b3[0];
  const f32x4 zc = {0.f, 0.f, 0.f, 0.f};

#pragma unroll 1
  for (int chunk = blockIdx.x; chunk < NCHUNK; chunk += EDGE_GRID) {
    const int ebase = chunk * 256 + w * 64;
    // Chunk-level coalesced loads of this wave's 64 edges.
    const int src_all = eidx[ebase + lane];
    const int dst_all = eidx[EDGES + ebase + lane];
    unsigned int ea_pk[4];
    {
      const f4* eap = (const f4*)(eattr + (size_t)(ebase + lane) * 8);
      f4 a0 = eap[0], a1 = eap[1];
      ea_pk[0] = (unsigned int)(unsigned short)f2bf_hw(a0[0]) |
                 ((unsigned int)(unsigned short)f2bf_hw(a0[1]) << 16);
      ea_pk[1] = (unsigned int)(unsigned short)f2bf_hw(a0[2]) |
                 ((unsigned int)(unsigned short)f2bf_hw(a0[3]) << 16);
      ea_pk[2] = (unsigned int)(unsigned short)f2bf_hw(a1[0]) |
                 ((unsigned int)(unsigned short)f2bf_hw(a1[1]) << 16);
      ea_pk[3] = (unsigned int)(unsigned short)f2bf_hw(a1[2]) |
                 ((unsigned int)(unsigned short)f2bf_hw(a1[3]) << 16);
    }

#pragma unroll
    for (int st = 0; st < 4; ++st) {
      const int e0 = ebase + st * 16;
      const int idx = st * 16 + r;
      const int srcv = __shfl(src_all, idx, 64);
      const int dstv = __shfl(dst_all, idx, 64);
      union { unsigned int u[4]; s8v v; } eau;
#pragma unroll
      for (int c = 0; c < 4; ++c) eau.u[c] = (unsigned int)__shfl((int)ea_pk[c], idx, 64);
      const s8v eaf = eau.v;  // valid k<8 (g==0); others hit zero A rows

      // B-operand gather: lanes g<2 read src's P half, g>=2 read dst's Q half.
      const unsigned short* base =
          (g < 2) ? (PQ + (size_t)srcv * 256 + 8 * (g & 1))
                  : (PQ + (size_t)dstv * 256 + 128 + 8 * (g & 1));
      u16x8 bpq[8];
#pragma unroll
      for (int kt = 0; kt < 4; ++kt) {
        bpq[2 * kt]     = *(const u16x8*)(base + 32 * kt);
        bpq[2 * kt + 1] = *(const u16x8*)(base + 32 * kt + 16);
      }

      f32x4 acc[4] = {zc, zc, zc, zc};
#pragma unroll
      for (int kt = 0; kt < 4; ++kt) {
        f32x4 E0 = __builtin_amdgcn_mfma_f32_16x16x32_bf16(w1cf[2 * kt], eaf, zc, 0, 0, 0);
        f32x4 E1 = __builtin_amdgcn_mfma_f32_16x16x32_bf16(w1cf[2 * kt + 1], eaf, zc, 0, 0, 0);
        f32x4 S0 = __builtin_amdgcn_mfma_f32_16x16x32_bf16(a_id, (s8v)bpq[2 * kt], E0, 0, 0, 0);
        f32x4 S1 = __builtin_amdgcn_mfma_f32_16x16x32_bf16(a_id, (s8v)bpq[2 * kt + 1], E1, 0, 0, 0);
        s8v af;
#pragma unroll
        for (int jp = 0; jp < 4; ++jp) {
          af[jp]     = f2bf_hw(fmaxf(S0[jp], 0.f));
          af[4 + jp] = f2bf_hw(fmaxf(S1[jp], 0.f));
        }
#pragma unroll
        for (int nt = 0; nt < 4; ++nt)
          acc[nt] = __builtin_amdgcn_mfma_f32_16x16x32_bf16(af, bfrag[kt][nt], acc[nt], 0, 0, 0);
      }
      // Layer 3 + 16-lane butterfly. Lane (g,r): C[edge=4g+reg][i=nt*16+r].
      float pr0 = 0.f, pr1 = 0.f, pr2 = 0.f, pr3 = 0.f;
#pragma unroll
      for (int nt = 0; nt < 4; ++nt) {
        pr0 = fmaf(fmaxf(acc[nt][0] + b2v[nt], 0.f), w3v[nt], pr0);
        pr1 = fmaf(fmaxf(acc[nt][1] + b2v[nt], 0.f), w3v[nt], pr1);
        pr2 = fmaf(fmaxf(acc[nt][2] + b2v[nt], 0.f), w3v[nt], pr2);
        pr3 = fmaf(fmaxf(acc[nt][3] + b2v[nt], 0.f), w3v[nt], pr3);
      }
#pragma unroll
      for (int m = 1; m < 16; m <<= 1) {
        pr0 += __shfl_xor(pr0, m, 64);
        pr1 += __shfl_xor(pr1, m, 64);
        pr2 += __shfl_xor(pr2, m, 64);
        pr3 += __shfl_xor(pr3, m, 64);
      }
      if (r < 4) {
        float v = (r == 0) ? pr0 : (r == 1) ? pr1 : (r == 2) ? pr2 : pr3;
        out[e0 + 4 * g + r] = v + bias3;
      }
    }
  }
}

extern "C" void kernel_launch(void* const* d_in, const int* in_sizes, int n_in,
                              void* d_out, int out_size, void* d_ws, size_t ws_size,
                              hipStream_t stream) {
  const float* z     = (const float*)d_in[0];
  const int*   eidx  = (const int*)d_in[1];
  const float* eattr = (const float*)d_in[2];
  const float* W1    = (const float*)d_in[3];
  const float* b1    = (const float*)d_in[4];
  const float* W2    = (const float*)d_in[5];
  const float* b2    = (const float*)d_in[6];
  const float* W3    = (const float*)d_in[7];
  const float* b3    = (const float*)d_in[8];
  float* out = (float*)d_out;

  unsigned short* PQ = (unsigned short*)d_ws;  // 51.2 MB
  node_pq_mfma<<<(NTILES + 3) / 4, 256, 0, stream>>>(z, W1, b1, PQ);
  edge_mfma_kernel<<<EDGE_GRID, 256, 0, stream>>>(
      eidx, eattr, W1, W2, b2, W3, b3, PQ, out);
}

// Round 6
// 175.595 us; speedup vs baseline: 6.7701x; 1.1462x over previous
//
#include <hip/hip_runtime.h>
#include <hip/hip_bf16.h>
#include <stdint.h>
#include <stddef.h>

#define NODES 100000
#define EDGES 1600000
#define NCHUNK 6250    // EDGES / 256
#define EDGE_GRID 3125 // 2 chunks per block, exact
#define NTILES 6250    // NODES / 16

typedef float f4 __attribute__((ext_vector_type(4)));
typedef float f32x4 __attribute__((ext_vector_type(4)));
typedef short s8v __attribute__((ext_vector_type(8)));     // bf16x8 MFMA frag
typedef unsigned short u16x8 __attribute__((ext_vector_type(8)));

__device__ __forceinline__ float bf2f(unsigned short u) {
  union { unsigned int i; float f; } v; v.i = ((unsigned int)u) << 16; return v.f;
}
__device__ __forceinline__ unsigned short f2bf(float f) {  // RNE (setup/stores)
  union { float f; unsigned int i; } v; v.f = f;
  return (unsigned short)((v.i + 0x7FFFu + ((v.i >> 16) & 1u)) >> 16);
}
__device__ __forceinline__ short f2bf_hw(float x) {        // hot path: HW cvt
  __hip_bfloat16 h = __float2bfloat16(x);
  union { __hip_bfloat16 h; short s; } u; u.h = h; return u.s;
}

// PQ column permutation: jj = kt<<5 | h<<4 | g<<2 | jp  ->  off = kt<<5 | g<<3 | h<<2 | jp
__device__ __forceinline__ int pqperm(int jj) {
  return (jj & 0x60) | ((jj & 0x0C) << 1) | ((jj & 0x10) >> 2) | (jj & 3);
}

// ---------------------------------------------------------------------------
// Kernel 1 (MFMA): PQ[n][perm(jj)]     = z[n] @ W1[0:64,jj]  + b1[jj]
//                  PQ[n][128+perm(jj)] = z[n] @ W1[64:128,jj]
// z and W1 split hi/lo bf16, 3-term MFMA products => f32-grade precision.
// One wave per 16-node tile.
// ---------------------------------------------------------------------------
__global__ __launch_bounds__(256) void node_pq_mfma(
    const float* __restrict__ z, const float* __restrict__ W1,
    const float* __restrict__ b1, unsigned short* __restrict__ PQ) {
  const int t = threadIdx.x;
  const int lane = t & 63;
  const int w = t >> 6;
  const int r = lane & 15, g = lane >> 4;
  const int tile = blockIdx.x * 4 + w;
  if (tile >= NTILES) return;
  const int n0 = tile * 16;

  s8v a_hi[2], a_lo[2];
#pragma unroll
  for (int kt = 0; kt < 2; ++kt) {
    const f4* zp = (const f4*)(z + (size_t)(n0 + r) * 64 + 32 * kt + 8 * g);
    f4 z0 = zp[0], z1 = zp[1];
    float zv[8] = {z0[0], z0[1], z0[2], z0[3], z1[0], z1[1], z1[2], z1[3]};
    s8v hi, lo;
#pragma unroll
    for (int jx = 0; jx < 8; ++jx) {
      short h = f2bf_hw(zv[jx]);
      hi[jx] = h;
      lo[jx] = f2bf_hw(zv[jx] - bf2f((unsigned short)h));
    }
    a_hi[kt] = hi; a_lo[kt] = lo;
  }

#pragma unroll 1
  for (int nt = 0; nt < 16; ++nt) {
    const int col = (nt & 7) * 16 + r;
    const int rowbase = (nt < 8) ? 0 : 64;
    const float init = (nt < 8) ? b1[col] : 0.f;
    f32x4 acc = {init, init, init, init};
#pragma unroll
    for (int kt = 0; kt < 2; ++kt) {
      s8v whi, wlo;
#pragma unroll
      for (int jx = 0; jx < 8; ++jx) {
        float wv = W1[(size_t)(rowbase + 32 * kt + 8 * g + jx) * 128 + col];
        short h = f2bf_hw(wv);
        whi[jx] = h;
        wlo[jx] = f2bf_hw(wv - bf2f((unsigned short)h));
      }
      acc = __builtin_amdgcn_mfma_f32_16x16x32_bf16(a_hi[kt], whi, acc, 0, 0, 0);
      acc = __builtin_amdgcn_mfma_f32_16x16x32_bf16(a_lo[kt], whi, acc, 0, 0, 0);
      acc = __builtin_amdgcn_mfma_f32_16x16x32_bf16(a_hi[kt], wlo, acc, 0, 0, 0);
    }
    const int outcol = (nt < 8) ? pqperm(col) : (128 + pqperm(col));
#pragma unroll
    for (int reg = 0; reg < 4; ++reg)
      PQ[(size_t)(n0 + 4 * g + reg) * 256 + outcol] = f2bf(acc[reg]);
  }
}

// ---------------------------------------------------------------------------
// Kernel 2: round-4 VALU-assembly MFMA edge kernel + explicit 1-deep
// double-buffered sub-tile gather pipeline (all indices hoisted, static).
// ---------------------------------------------------------------------------
__global__ __launch_bounds__(256) void edge_mfma_kernel(
    const int* __restrict__ eidx, const float* __restrict__ eattr,
    const float* __restrict__ W1, const float* __restrict__ W2,
    const float* __restrict__ b2, const float* __restrict__ W3,
    const float* __restrict__ b3,
    const unsigned short* __restrict__ PQ, float* __restrict__ out) {
  const int t = threadIdx.x;
  const int lane = t & 63;
  const int w = t >> 6;
  const int r = lane & 15;   // edge row (A side) / col (C side)
  const int g = lane >> 4;   // k-group

  // Persistent W2 B-frags: jj(kt,g,jx) = 32kt + 16(jx>>2) + 4g + (jx&3)
  s8v bfrag[4][4];
#pragma unroll
  for (int kt = 0; kt < 4; ++kt)
#pragma unroll
    for (int nt = 0; nt < 4; ++nt) {
      s8v f;
#pragma unroll
      for (int jx = 0; jx < 8; ++jx) {
        int h = jx >> 2, jp = jx & 3;
        int jjv = 32 * kt + 16 * h + 4 * g + jp;
        f[jx] = (short)f2bf(W2[(size_t)jjv * 64 + nt * 16 + r]);
      }
      bfrag[kt][nt] = f;
    }
  // W1c A-frags for the E-mfma (k-slot = 8g+jx; nonzero only g==0).
  s8v w1cf[8];
#pragma unroll
  for (int mt = 0; mt < 8; ++mt) {
    s8v f = {0, 0, 0, 0, 0, 0, 0, 0};
    if (g == 0) {
#pragma unroll
      for (int jx = 0; jx < 8; ++jx)
        f[jx] = (short)f2bf(W1[(size_t)(128 + jx) * 128 + 16 * mt + r]);
    }
    w1cf[mt] = f;
  }
  float b2v[4], w3v[4];
#pragma unroll
  for (int nt = 0; nt < 4; ++nt) { b2v[nt] = b2[nt * 16 + r]; w3v[nt] = W3[nt * 16 + r]; }
  const float bias3 = b3[0];
  const f32x4 zc = {0.f, 0.f, 0.f, 0.f};

#pragma unroll 1
  for (int chunk = blockIdx.x; chunk < NCHUNK; chunk += EDGE_GRID) {
    const int ebase = chunk * 256 + w * 64;
    const int src_all = eidx[ebase + lane];
    const int dst_all = eidx[EDGES + ebase + lane];
    unsigned int ea_pk[4];
    {
      const f4* eap = (const f4*)(eattr + (size_t)(ebase + lane) * 8);
      f4 a0 = eap[0], a1 = eap[1];
      ea_pk[0] = (unsigned int)(unsigned short)f2bf_hw(a0[0]) |
                 ((unsigned int)(unsigned short)f2bf_hw(a0[1]) << 16);
      ea_pk[1] = (unsigned int)(unsigned short)f2bf_hw(a0[2]) |
                 ((unsigned int)(unsigned short)f2bf_hw(a0[3]) << 16);
      ea_pk[2] = (unsigned int)(unsigned short)f2bf_hw(a1[0]) |
                 ((unsigned int)(unsigned short)f2bf_hw(a1[1]) << 16);
      ea_pk[3] = (unsigned int)(unsigned short)f2bf_hw(a1[2]) |
                 ((unsigned int)(unsigned short)f2bf_hw(a1[3]) << 16);
    }

    // Hoisted per-sub-tile indices / attrs (shuffles only, no memory).
    int srcv[4], dstv[4];
    s8v eafv[4];
#pragma unroll
    for (int st = 0; st < 4; ++st) {
      const int idx = st * 16 + r;
      srcv[st] = __shfl(src_all, idx, 64);
      dstv[st] = __shfl(dst_all, idx, 64);
      union { unsigned int u[4]; s8v v; } eu;
#pragma unroll
      for (int c = 0; c < 4; ++c) eu.u[c] = (unsigned int)__shfl((int)ea_pk[c], idx, 64);
      eafv[st] = eu.v;
    }

    u16x8 p[4][4], q[4][4];
#define PQ_LOAD(s)                                                             \
    {                                                                          \
      const unsigned short* Pb = PQ + (size_t)srcv[s] * 256 + 8 * g;           \
      const unsigned short* Qb = PQ + (size_t)dstv[s] * 256 + 128 + 8 * g;     \
      _Pragma("unroll")                                                        \
      for (int kt = 0; kt < 4; ++kt) {                                         \
        p[s][kt] = *(const u16x8*)(Pb + 32 * kt);                              \
        q[s][kt] = *(const u16x8*)(Qb + 32 * kt);                              \
      }                                                                        \
    }

#define PQ_COMPUTE(s)                                                          \
    {                                                                          \
      const int e0 = ebase + (s) * 16;                                         \
      f32x4 acc[4] = {zc, zc, zc, zc};                                         \
      _Pragma("unroll")                                                        \
      for (int kt = 0; kt < 4; ++kt) {                                         \
        f32x4 E0 = __builtin_amdgcn_mfma_f32_16x16x32_bf16(w1cf[2 * kt], eafv[s], zc, 0, 0, 0); \
        f32x4 E1 = __builtin_amdgcn_mfma_f32_16x16x32_bf16(w1cf[2 * kt + 1], eafv[s], zc, 0, 0, 0); \
        s8v af;                                                                \
        _Pragma("unroll")                                                      \
        for (int jp = 0; jp < 4; ++jp) {                                       \
          float s0 = bf2f(p[s][kt][jp]) + bf2f(q[s][kt][jp]) + E0[jp];         \
          af[jp] = f2bf_hw(fmaxf(s0, 0.f));                                    \
          float s1 = bf2f(p[s][kt][4 + jp]) + bf2f(q[s][kt][4 + jp]) + E1[jp]; \
          af[4 + jp] = f2bf_hw(fmaxf(s1, 0.f));                                \
        }                                                                      \
        _Pragma("unroll")                                                      \
        for (int nt = 0; nt < 4; ++nt)                                         \
          acc[nt] = __builtin_amdgcn_mfma_f32_16x16x32_bf16(af, bfrag[kt][nt], acc[nt], 0, 0, 0); \
      }                                                                        \
      float pr0 = 0.f, pr1 = 0.f, pr2 = 0.f, pr3 = 0.f;                        \
      _Pragma("unroll")                                                        \
      for (int nt = 0; nt < 4; ++nt) {                                         \
        pr0 = fmaf(fmaxf(acc[nt][0] + b2v[nt], 0.f), w3v[nt], pr0);            \
        pr1 = fmaf(fmaxf(acc[nt][1] + b2v[nt], 0.f), w3v[nt], pr1);            \
        pr2 = fmaf(fmaxf(acc[nt][2] + b2v[nt], 0.f), w3v[nt], pr2);            \
        pr3 = fmaf(fmaxf(acc[nt][3] + b2v[nt], 0.f), w3v[nt], pr3);            \
      }                                                                        \
      _Pragma("unroll")                                                        \
      for (int m = 1; m < 16; m <<= 1) {                                       \
        pr0 += __shfl_xor(pr0, m, 64);                                         \
        pr1 += __shfl_xor(pr1, m, 64);                                         \
        pr2 += __shfl_xor(pr2, m, 64);                                         \
        pr3 += __shfl_xor(pr3, m, 64);                                         \
      }                                                                        \
      if (r < 4) {                                                             \
        float v = (r == 0) ? pr0 : (r == 1) ? pr1 : (r == 2) ? pr2 : pr3;      \
        out[e0 + 4 * g + r] = v + bias3;                                       \
      }                                                                        \
    }

    PQ_LOAD(0)
    PQ_LOAD(1)
    PQ_COMPUTE(0)
    PQ_LOAD(2)
    PQ_COMPUTE(1)
    PQ_LOAD(3)
    PQ_COMPUTE(2)
    PQ_COMPUTE(3)
#undef PQ_LOAD
#undef PQ_COMPUTE
  }
}

extern "C" void kernel_launch(void* const* d_in, const int* in_sizes, int n_in,
                              void* d_out, int out_size, void* d_ws, size_t ws_size,
                              hipStream_t stream) {
  const float* z     = (const float*)d_in[0];
  const int*   eidx  = (const int*)d_in[1];
  const float* eattr = (const float*)d_in[2];
  const float* W1    = (const float*)d_in[3];
  const float* b1    = (const float*)d_in[4];
  const float* W2    = (const float*)d_in[5];
  const float* b2    = (const float*)d_in[6];
  const float* W3    = (const float*)d_in[7];
  const float* b3    = (const float*)d_in[8];
  float* out = (float*)d_out;

  unsigned short* PQ = (unsigned short*)d_ws;  // 51.2 MB
  node_pq_mfma<<<(NTILES + 3) / 4, 256, 0, stream>>>(z, W1, b1, PQ);
  edge_mfma_kernel<<<EDGE_GRID, 256, 0, stream>>>(
      eidx, eattr, W1, W2, b2, W3, b3, PQ, out);
}